// Round 22
// baseline (72.008 us; speedup 1.0000x reference)
//
#include <hip/hip_runtime.h>
#include <hip/hip_bf16.h>

// Problem constants
#define BATCH   8192
#define NGRP    8
#define MAXGS   64
#define DMODEL  2048
#define TM      16
#define NBLK    32
#define KC      256               // f32 per chunk-row
#define NCH     (DMODEL / KC)     // 8 chunks
#define KKP     (KC / 32)         // 8 kk per chunk
#define MAXTILES 520

typedef __attribute__((ext_vector_type(8))) short  short8;
typedef __attribute__((ext_vector_type(4))) float  f32x4;

// ws layout
#define CNT_OFF   0
#define HIST_OFF  512
#define MAP_OFF   1536
#define LISTS_OFF 4096
#define CNT_STRIDE 16

static __device__ __forceinline__ short bf(float f) {
    __hip_bfloat16 h = __float2bfloat16(f);
    return (short)__bfloat16_as_ushort(h);
}

// Phase 0: per-block group histograms only (the 48MB W-repack kernel is GONE
// -- its work is fused into gemm, overlapping the W read with the A gather).
__global__ __launch_bounds__(256) void hist_kernel(const int* __restrict__ chosen,
                                                   int* __restrict__ hist) {
    int tid = threadIdx.x;
    __shared__ int h[NGRP];
    if (tid < NGRP) h[tid] = 0;
    __syncthreads();
    int g = chosen[blockIdx.x * 256 + tid];
    atomicAdd(&h[g], 1);
    __syncthreads();
    if (tid < NGRP) hist[blockIdx.x * NGRP + tid] = h[tid];
}

// Phase 1: scan fused into scatter + tile directory (unchanged from r21).
__global__ __launch_bounds__(256) void scatter_kernel(const int* __restrict__ chosen,
                                                      const int* __restrict__ hist,
                                                      int* __restrict__ lists,
                                                      int* __restrict__ cnt,
                                                      int* __restrict__ map) {
    __shared__ int hloc[NBLK * NGRP];
    __shared__ int gbase[NGRP];
    __shared__ int ntl[NGRP];
    __shared__ int wcnt[4][NGRP];
    __shared__ int wbase[4][NGRP];
    int tid  = threadIdx.x;
    int blk  = blockIdx.x;
    int w    = tid >> 6;
    int lane = tid & 63;

    if (tid < NBLK * NGRP) hloc[tid] = hist[tid];
    __syncthreads();
    if (tid < NGRP) {
        int s = 0;
        for (int b2 = 0; b2 < blk; ++b2) s += hloc[b2 * NGRP + tid];
        gbase[tid] = s;
        int tot = s;
        for (int b2 = blk; b2 < NBLK; ++b2) tot += hloc[b2 * NGRP + tid];
        ntl[tid] = (tot + TM - 1) / TM;
        if (blk == 0) cnt[tid * CNT_STRIDE] = tot;
    }
    __syncthreads();

    if (blk == 0) {
        for (int q = tid; q < MAXTILES; q += 256) map[q] = -1;
        __syncthreads();
        for (int p = tid; p < NGRP * 512; p += 256) {
            int t = p >> 3, gg = p & 7;
            if (t < ntl[gg]) {
                int pos = 0;
                #pragma unroll
                for (int g2 = 0; g2 < NGRP; ++g2) {
                    int nt = ntl[g2];
                    pos += (t < nt ? t : nt);
                    pos += (g2 < gg && nt > t) ? 1 : 0;
                }
                map[pos] = (gg << 16) | t;
            }
        }
    }

    int b = blk * 256 + tid;
    int g = chosen[b];
    int rank = 0;
    unsigned long long below = (1ull << lane) - 1ull;
    #pragma unroll
    for (int gg = 0; gg < NGRP; ++gg) {
        unsigned long long m = __ballot(g == gg);
        if (g == gg) rank = __popcll(m & below);
        if (lane == gg) wcnt[w][gg] = __popcll(m);
    }
    __syncthreads();
    if (tid < NGRP) {
        int base = gbase[tid];
        #pragma unroll
        for (int ww = 0; ww < 4; ++ww) {
            wbase[ww][tid] = base;
            base += wcnt[ww][tid];
        }
    }
    __syncthreads();
    lists[g * BATCH + wbase[w][g] + rank] = b;
}

// Phase 2: fused gemm — A AND B staged to LDS per K-chunk; inner loop is
// VMEM-FREE (only ds_read + MFMA), so LOAD(ch+1)'s global loads stay in
// flight under COMPUTE(ch): the in-order-vmcnt pollution that defeated
// r7/r16/r17/r21 is structurally impossible (no VMEM waits inside compute).
// B staged from RAW f32 W in 1KB-contiguous per-column bursts (no 4KB-stride
// channel pileup; W[g]=4MB L2-resident per XCD via g=XCD alignment).
// Swizzles (verified 8-lanes-per-16B-slot = the b128 floor):
//   swzA(r)  = ((r&3)<<4)   | (((r>>3)&1)<<6)
//   swzB(cl) = ((cl&3)<<4)  | (((cl>>2)&1)<<6)
// LDS = 2 x (8KB A + 32KB B) = 80KB -> 2 blocks/CU (matches 520-block grid).
__global__ __launch_bounds__(256, 2) void gemm_kernel(
    const float* __restrict__ hidden,
    const float* __restrict__ W,
    const float* __restrict__ bias,
    const int* __restrict__ gsizes,
    const int* __restrict__ cnt,
    const int* __restrict__ lists,
    const int* __restrict__ map,
    float* __restrict__ out)
{
    int e = map[blockIdx.x];
    if (e < 0) return;             // sentinel (<=8)
    int g = e >> 16;
    int t = e & 0xFFFF;
    int c = cnt[g * CNT_STRIDE];
    int m0 = t * TM;

    __shared__ unsigned short As[2][TM][KC];      // 16 KB
    __shared__ unsigned short Bs[2][MAXGS][KC];   // 64 KB

    int tid  = threadIdx.x;
    int w    = tid >> 6;           // wave 0..3
    int lane = tid & 63;
    int lrow = lane & 15;
    int kg   = lane >> 4;          // 0..3 (= q for staging)

    // --- staging sources ---
    // A: row r = 4w + kg; lane's k-slice = [lrow*16, +16) f32 of each chunk
    int arow = 4 * w + kg;
    int am   = m0 + arow;
    int ams  = am < c ? am : c - 1;              // tail: dup last row (guarded)
    const float* asrc = hidden + ((size_t)lists[g * BATCH + ams] * NGRP + g) * DMODEL
                      + lrow * 16;
    // B: col = 16w + lrow; lane's k-slice = [kg*64, +64) f32 of each chunk
    int bcol = 16 * w + lrow;
    const float* bsrc = W + ((size_t)g * MAXGS + bcol) * DMODEL + kg * 64;

    int swzA_w = ((arow & 3) << 4) | (((arow >> 3) & 1) << 6);   // write-side A
    int swzB_w = ((bcol & 3) << 4) | (((bcol >> 2) & 1) << 6);   // write-side B
    int swzA_r = ((lrow & 3) << 4) | (((lrow >> 3) & 1) << 6);   // read-side A
    int swzB_r = ((lrow & 3) << 4) | (((lrow >> 2) & 1) << 6);   // read-side B
                                                                 // (16w drops out)
    f32x4 ar[4];    // 16 f32 (A slice)
    f32x4 br[16];   // 64 f32 (B slice)

    auto LOAD = [&](int ch) {
        #pragma unroll
        for (int j = 0; j < 4; ++j)
            ar[j] = *reinterpret_cast<const f32x4*>(asrc + ch * KC + j * 4);
        #pragma unroll
        for (int j = 0; j < 16; ++j)
            br[j] = *reinterpret_cast<const f32x4*>(bsrc + ch * KC + j * 4);
    };
    auto WRITE = [&](int buf) {
        char* ab = (char*)&As[buf][arow][0];
        #pragma unroll
        for (int j2 = 0; j2 < 2; ++j2) {
            short8 o;
            #pragma unroll
            for (int q2 = 0; q2 < 2; ++q2) {
                f32x4 v = ar[j2 * 2 + q2];
                o[q2*4+0] = bf(v[0]); o[q2*4+1] = bf(v[1]);
                o[q2*4+2] = bf(v[2]); o[q2*4+3] = bf(v[3]);
            }
            *reinterpret_cast<short8*>(ab + ((lrow * 32 + j2 * 16) ^ swzA_w)) = o;
        }
        char* bb = (char*)&Bs[buf][bcol][0];
        #pragma unroll
        for (int i = 0; i < 8; ++i) {
            short8 o;
            #pragma unroll
            for (int q2 = 0; q2 < 2; ++q2) {
                f32x4 v = br[i * 2 + q2];
                o[q2*4+0] = bf(v[0]); o[q2*4+1] = bf(v[1]);
                o[q2*4+2] = bf(v[2]); o[q2*4+3] = bf(v[3]);
            }
            *reinterpret_cast<short8*>(bb + ((kg * 128 + i * 16) ^ swzB_w)) = o;
        }
    };

    f32x4 acc = f32x4{0, 0, 0, 0};

    LOAD(0);
    WRITE(0);                      // compiler inserts the vmcnt waits for ar/br
    __syncthreads();
    #pragma unroll
    for (int ch = 0; ch < NCH; ++ch) {
        if (ch + 1 < NCH) LOAD(ch + 1);          // global loads in flight...
        const char* abase = (const char*)&As[ch & 1][lrow][0];
        const char* bbase = (const char*)&Bs[ch & 1][bcol][0];
        #pragma unroll
        for (int k2 = 0; k2 < KKP; ++k2) {       // ...hidden under LDS+MFMA
            int kb = k2 * 64 + kg * 16;
            short8 af  = *reinterpret_cast<const short8*>(abase + (kb ^ swzA_r));
            short8 bfr = *reinterpret_cast<const short8*>(bbase + (kb ^ swzB_r));
            acc = __builtin_amdgcn_mfma_f32_16x16x32_bf16(af, bfr, acc, 0, 0, 0);
        }
        if (ch + 1 < NCH) WRITE((ch + 1) & 1);   // waits vmcnt; buf disjoint
        __syncthreads();
    }

    // epilogue: C col = lrow -> n = 16w+lrow, row = kg*4 + r
    int gsz = gsizes[g];
    int n = 16 * w + lrow;
    float bv = bias[g * MAXGS + n];
    #pragma unroll
    for (int r = 0; r < 4; ++r) {
        int m = m0 + kg * 4 + r;
        if (m < c) {
            int s = lists[g * BATCH + m];
            out[(size_t)s * MAXGS + n] = acc[r] + bv;   // padded n: 0+0 == 0
            out[(size_t)(BATCH + s) * MAXGS + n] = (n < gsz) ? 1.0f : 0.0f;
        }
    }
}

extern "C" void kernel_launch(void* const* d_in, const int* in_sizes, int n_in,
                              void* d_out, int out_size, void* d_ws, size_t ws_size,
                              hipStream_t stream) {
    const float* hidden = (const float*)d_in[0];   // [8192, 8, 2048] f32
    const int*   chosen = (const int*)d_in[1];     // [8192] i32
    const float* W      = (const float*)d_in[2];   // [8, 64, 2048] f32 (zero-padded)
    const float* bias   = (const float*)d_in[3];   // [8, 64] f32 (zero-padded)
    const int*   gs     = (const int*)d_in[4];     // [8] i32
    float* out = (float*)d_out;                    // [8192*64 preds | 8192*64 valid]

    char* ws = (char*)d_ws;
    int* cnt   = (int*)(ws + CNT_OFF);
    int* hist  = (int*)(ws + HIST_OFF);
    int* map   = (int*)(ws + MAP_OFF);
    int* lists = (int*)(ws + LISTS_OFF);

    hist_kernel<<<dim3(NBLK), dim3(256), 0, stream>>>(chosen, hist);
    scatter_kernel<<<dim3(NBLK), dim3(256), 0, stream>>>(chosen, hist, lists, cnt, map);
    gemm_kernel<<<dim3(MAXTILES), dim3(256), 0, stream>>>(
        hidden, W, bias, gs, cnt, lists, map, out);
}

// Round 23
// 34.130 us; speedup vs baseline: 2.1098x; 2.1098x over previous
//
#include <hip/hip_runtime.h>
#include <hip/hip_bf16.h>

// Problem constants
#define BATCH   8192
#define NGRP    8
#define MAXGS   64
#define DMODEL  2048
#define TM      16
#define NBLK    32
#define NKK     (DMODEL / 32)     // 64 K-chunks of 32
#define KC      128               // f32 per phase per row
#define NPH     (DMODEL / KC)     // 16 phases
#define RING    8                 // 8 x [16][128] f32 = 64 KB
#define PFD     6                 // prefetch depth (phases)
#define NTHR    384               // 2 producer + 4 consumer waves

typedef __attribute__((ext_vector_type(8))) short  short8;
typedef __attribute__((ext_vector_type(4))) float  f32x4;

// ws layout
#define CNT_OFF   0
#define HIST_OFF  512
#define LISTS_OFF 4096
#define W_OFF     (LISTS_OFF + NGRP * BATCH * 4)
#define CNT_STRIDE 16

static __device__ __forceinline__ short bf(float f) {
    __hip_bfloat16 h = __float2bfloat16(f);
    return (short)__bfloat16_as_ushort(h);
}

// async global->LDS DMA, 16B/lane; dest wave-uniform + lane*16 (linear);
// source per-lane (carries the pre-applied swizzle).
static __device__ __forceinline__ void gload_lds16(const float* src, float* lds) {
    __builtin_amdgcn_global_load_lds(
        (const __attribute__((address_space(1))) unsigned int*)src,
        (__attribute__((address_space(3))) unsigned int*)lds,
        16, 0, 0);
}

// Phase 0 (fused): blocks < 1024 repack W f32 [g][c][k] -> bf16 Wb2
// [g][kk][c][j] (per-MFMA B-load = 1KB contiguous, Wall-B fix, r15-proven).
// Blocks >= 1024: per-block group histogram of `chosen`.
__global__ __launch_bounds__(256) void init_hist_kernel(
    const float* __restrict__ W,
    const int* __restrict__ chosen,
    unsigned short* __restrict__ Wb2,
    int* __restrict__ hist)
{
    int blk = blockIdx.x;
    int tid = threadIdx.x;
    if (blk < 1024) {
        int e = (blk * 256 + tid) * 4;
        int g = e >> 17;
        int rem = e & ((MAXGS * DMODEL) - 1);
        int c = rem >> 11;
        int k = rem & (DMODEL - 1);
        int kk = k >> 5, j = k & 31;
        float4 w = *reinterpret_cast<const float4*>(W + e);
        ushort4 o;
        o.x = (unsigned short)bf(w.x); o.y = (unsigned short)bf(w.y);
        o.z = (unsigned short)bf(w.z); o.w = (unsigned short)bf(w.w);
        size_t dst = (((size_t)g * NKK + kk) * MAXGS + c) * 32 + j;
        *reinterpret_cast<ushort4*>(Wb2 + dst) = o;
    } else {
        int hb = blk - 1024;
        __shared__ int h[NGRP];
        if (tid < NGRP) h[tid] = 0;
        __syncthreads();
        int g = chosen[hb * 256 + tid];
        atomicAdd(&h[g], 1);
        __syncthreads();
        if (tid < NGRP) hist[hb * NGRP + tid] = h[tid];
    }
}

// Phase 1: scan fused into scatter; deterministic ascending-b ballot ranks.
__global__ __launch_bounds__(256) void scatter_kernel(const int* __restrict__ chosen,
                                                      const int* __restrict__ hist,
                                                      int* __restrict__ lists,
                                                      int* __restrict__ cnt) {
    __shared__ int hloc[NBLK * NGRP];
    __shared__ int gbase[NGRP];
    __shared__ int wcnt[4][NGRP];
    __shared__ int wbase[4][NGRP];
    int tid  = threadIdx.x;
    int blk  = blockIdx.x;
    int w    = tid >> 6;
    int lane = tid & 63;

    if (tid < NBLK * NGRP) hloc[tid] = hist[tid];
    __syncthreads();
    if (tid < NGRP) {
        int s = 0;
        for (int b2 = 0; b2 < blk; ++b2) s += hloc[b2 * NGRP + tid];
        gbase[tid] = s;
        if (blk == 0) {
            int tot = 0;
            for (int b2 = 0; b2 < NBLK; ++b2) tot += hloc[b2 * NGRP + tid];
            cnt[tid * CNT_STRIDE] = tot;
        }
    }

    int b = blk * 256 + tid;
    int g = chosen[b];
    int rank = 0;
    unsigned long long below = (1ull << lane) - 1ull;
    #pragma unroll
    for (int gg = 0; gg < NGRP; ++gg) {
        unsigned long long m = __ballot(g == gg);
        if (g == gg) rank = __popcll(m & below);
        if (lane == gg) wcnt[w][gg] = __popcll(m);
    }
    __syncthreads();
    if (tid < NGRP) {
        int base = gbase[tid];
        #pragma unroll
        for (int ww = 0; ww < 4; ++ww) {
            wbase[ww][tid] = base;
            base += wcnt[ww][tid];
        }
    }
    __syncthreads();
    lists[g * BATCH + wbase[w][g] + rank] = b;
}

// Phase 2: r8's DEEP-PIPELINED producer + coalesced-B consumer (the untested
// combination). r8's producer (global_load_lds ring-8, counted vmcnt(20),
// loads in flight ACROSS barriers, no VGPR round-trip) was invisible behind
// its Wall-B consumer (22us); r17's good-B consumer sat behind a SHALLOW
// producer (per-phase latency exposure + reg-write drain). This kernel has
// neither defect: producer queue = A-DMA only with counted waits; consumer
// queue = L2 B-loads only; A reaches consumers via ds_read (lgkm).
// A swizzle: LDS[r][x] = global[r][x ^ ((r&7)<<4)] via pre-swizzled per-lane
// SOURCE (DMA dest linear, rule 21); consumers XOR the same on ds_read ->
// rows r, r+8 share a 16B slot = 2-way = free.
__global__ __launch_bounds__(NTHR, 2) void gemm_kernel(
    const float* __restrict__ hidden,
    const float* __restrict__ bias,
    const int* __restrict__ gsizes,
    const int* __restrict__ cnt,
    const int* __restrict__ lists,
    const unsigned short* __restrict__ Wb2,
    float* __restrict__ out)
{
    int bid = blockIdx.x;
    int g = bid & (NGRP - 1);      // group <-> XCD alignment: Wb2[g] L2-resident
    int t = bid >> 3;
    int c = cnt[g * CNT_STRIDE];
    int m0 = t * TM;
    if (m0 >= c) return;           // uniform exit, before any barrier

    __shared__ float A[RING][TM][KC];   // 64 KB

    int tid  = threadIdx.x;
    int w    = tid >> 6;
    int lane = tid & 63;

    if (w < 2) {
        // ---------------- PRODUCER: wave w stages rows 8w .. 8w+7 ----------
        int xsw = (lane & 31) * 16;    // within-row byte offset of this lane
        const float *hb0, *hb1, *hb2, *hb3;
        #define MKHB(i, dst)                                                   \
            {                                                                  \
                int r  = 8 * w + 2 * (i) + (lane >> 5);                        \
                int m  = m0 + r;                                               \
                int ms = m < c ? m : c - 1;   /* tail: dup last row */         \
                dst = hidden + ((size_t)lists[g * BATCH + ms] * NGRP + g) * DMODEL \
                      + ((xsw ^ ((r & 7) << 4)) >> 2);                         \
            }
        MKHB(0, hb0) MKHB(1, hb1) MKHB(2, hb2) MKHB(3, hb3)
        #undef MKHB

        #define PSTAGE(ph)                                                     \
            {                                                                  \
                float* dst = &A[(ph) & (RING - 1)][8 * w][0];                  \
                gload_lds16(hb0 + (ph) * KC, dst + 0 * 2 * KC);                \
                gload_lds16(hb1 + (ph) * KC, dst + 1 * 2 * KC);                \
                gload_lds16(hb2 + (ph) * KC, dst + 2 * 2 * KC);                \
                gload_lds16(hb3 + (ph) * KC, dst + 3 * 2 * KC);                \
            }
        #define PWAIT(n) asm volatile("s_waitcnt vmcnt(" #n ")" ::: "memory")
        #define PBAR()   __builtin_amdgcn_s_barrier(); asm volatile("" ::: "memory")

        // prologue: fill depth-6 pipeline; retire stage(0) only (24 -> 20)
        PSTAGE(0) PSTAGE(1) PSTAGE(2) PSTAGE(3) PSTAGE(4) PSTAGE(5)
        PWAIT(20);
        // phases 0..9: issue stage(ch+6); retire stage(ch+1); 20 in flight
        #define PPH(ch)  PBAR(); PSTAGE((ch) + PFD) PWAIT(20);
        PPH(0) PPH(1) PPH(2) PPH(3) PPH(4) PPH(5) PPH(6) PPH(7) PPH(8) PPH(9)
        #undef PPH
        // phases 10..15: no new issues; progressively retire stage(ch+1)
        PBAR(); PWAIT(16);   // ch=10: stage(11) done
        PBAR(); PWAIT(12);   // ch=11
        PBAR(); PWAIT(8);    // ch=12
        PBAR(); PWAIT(4);    // ch=13
        PBAR(); PWAIT(0);    // ch=14: stage(15) done
        PBAR();              // ch=15: consumers finish buffer 15
        #undef PSTAGE
        #undef PWAIT
        #undef PBAR
    } else {
        // ---------------- CONSUMER: wave cw owns cols [16cw, 16cw+16) ------
        int cw   = w - 2;              // 0..3
        int lrow = lane & 15;
        int kg   = lane >> 4;          // 0..3
        int swzr = (lrow & 7) << 4;    // read-side XOR (bytes)
        // Coalesced B (Wall-B fix): wave covers 1KB contiguous per kk-slab.
        const unsigned short* bp =
            Wb2 + (size_t)g * NKK * MAXGS * 32 + (cw * 16 + lrow) * 32 + kg * 8;

        f32x4 acc = f32x4{0, 0, 0, 0};

        #pragma unroll
        for (int ch = 0; ch < NPH; ++ch) {
            __builtin_amdgcn_s_barrier();
            asm volatile("" ::: "memory");     // no LDS-read hoist above barrier
            const char* ab = (const char*)&A[ch & (RING - 1)][lrow][0];
            #pragma unroll
            for (int ks = 0; ks < KC / 32; ++ks) {
                int xb = ks * 128 + kg * 32;
                f32x4 alo = *reinterpret_cast<const f32x4*>(ab + ((xb) ^ swzr));
                f32x4 ahi = *reinterpret_cast<const f32x4*>(ab + ((xb + 16) ^ swzr));
                short8 af;
                af[0] = bf(alo[0]); af[1] = bf(alo[1]); af[2] = bf(alo[2]); af[3] = bf(alo[3]);
                af[4] = bf(ahi[0]); af[5] = bf(ahi[1]); af[6] = bf(ahi[2]); af[7] = bf(ahi[3]);
                short8 bfr = *reinterpret_cast<const short8*>(
                    bp + (size_t)(ch * (KC / 32) + ks) * MAXGS * 32);
                acc = __builtin_amdgcn_mfma_f32_16x16x32_bf16(af, bfr, acc, 0, 0, 0);
            }
        }

        // epilogue: C col = lane&15 (our n), row = kg*4 + r (sample in tile)
        int gsz = gsizes[g];
        int n = cw * 16 + lrow;
        float bv = bias[g * MAXGS + n];
        #pragma unroll
        for (int r = 0; r < 4; ++r) {
            int m = m0 + kg * 4 + r;
            if (m < c) {
                int s = lists[g * BATCH + m];
                out[(size_t)s * MAXGS + n] = acc[r] + bv;   // padded n: 0+0 == 0
                out[(size_t)(BATCH + s) * MAXGS + n] = (n < gsz) ? 1.0f : 0.0f;
            }
        }
    }
}

extern "C" void kernel_launch(void* const* d_in, const int* in_sizes, int n_in,
                              void* d_out, int out_size, void* d_ws, size_t ws_size,
                              hipStream_t stream) {
    const float* hidden = (const float*)d_in[0];   // [8192, 8, 2048] f32
    const int*   chosen = (const int*)d_in[1];     // [8192] i32
    const float* W      = (const float*)d_in[2];   // [8, 64, 2048] f32 (zero-padded)
    const float* bias   = (const float*)d_in[3];   // [8, 64] f32 (zero-padded)
    const int*   gs     = (const int*)d_in[4];     // [8] i32
    float* out = (float*)d_out;                    // [8192*64 preds | 8192*64 valid]

    char* ws = (char*)d_ws;
    int* cnt   = (int*)(ws + CNT_OFF);
    int* hist  = (int*)(ws + HIST_OFF);
    int* lists = (int*)(ws + LISTS_OFF);
    unsigned short* Wb2 = (unsigned short*)(ws + W_OFF);

    init_hist_kernel<<<dim3(1024 + NBLK), dim3(256), 0, stream>>>(W, chosen, Wb2, hist);
    scatter_kernel<<<dim3(NBLK), dim3(256), 0, stream>>>(chosen, hist, lists, cnt);
    gemm_kernel<<<dim3(NGRP * (BATCH / TM)), dim3(NTHR), 0, stream>>>(
        hidden, bias, gs, cnt, lists, Wb2, out);
}